// Round 7
// baseline (1613.763 us; speedup 1.0000x reference)
//
#include <hip/hip_runtime.h>
#include <math.h>
#include <stdint.h>

#define B_ROWS 4096
#define D_DIM  768
#define M_ROWS 100000
#define K_TOP  10

// ---------------- MFMA-path constants ----------------
#define KSTEPS 48          // 768 / 16
#define E32N   3125        // evidence 32-row tiles
#define B32N   128         // batch 32-row tiles
#define NGRP   16          // evidence groups
#define NBB    16          // batch blocks (256 rows each)
#define NITER_TOT 391      // ceil(3125/8)
#define CAND   12          // candidates kept per (row, group)
#define KCN    12          // k-chunks of 64
#define LTK    6           // per-lane top-k length

typedef _Float16 f16;
typedef _Float16 f16x8 __attribute__((ext_vector_type(8)));
typedef float   f32x16 __attribute__((ext_vector_type(16)));

// workspace layout (bytes)
#define XF_BYTES (128ull * 48 * 1024)
#define EF_OFF   XF_BYTES
#define EF_BYTES (3125ull * 48 * 1024)
#define CS_OFF   (EF_OFF + EF_BYTES)
#define CS_BYTES (4096ull * NGRP * CAND * 4)
#define CI_OFF   (CS_OFF + CS_BYTES)
#define CI_BYTES (4096ull * NGRP * CAND * 4)
#define WS_NEED  (CI_OFF + CI_BYTES)

// ---------------------------------------------------------------------------
// Convert fp32 [rows][768] -> f16 fragment-tiled [band32][ks48][lane64][j8].
// frag value (l,j) = src[band*32 + (l&31)][ks*16 + 8*(l>>5) + j]
// ---------------------------------------------------------------------------
__global__ __launch_bounds__(256) void convert_frag(
    const float* __restrict__ src, f16* __restrict__ dst, int nband)
{
  int tid  = blockIdx.x * 256 + threadIdx.x;
  int l    = tid & 63;
  int rest = tid >> 6;
  int ks   = rest % KSTEPS;
  int band = rest / KSTEPS;
  if (band >= nband) return;
  int row = band * 32 + (l & 31);
  int k0  = ks * 16 + 8 * (l >> 5);
  const float* s = src + (size_t)row * D_DIM + k0;
  float4 v0 = *(const float4*)s;
  float4 v1 = *(const float4*)(s + 4);
  f16x8 o;
  o[0] = (f16)v0.x; o[1] = (f16)v0.y; o[2] = (f16)v0.z; o[3] = (f16)v0.w;
  o[4] = (f16)v1.x; o[5] = (f16)v1.y; o[6] = (f16)v1.z; o[7] = (f16)v1.w;
  *(f16x8*)(dst + (((size_t)band * KSTEPS + ks) << 9) + l * 8) = o;
}

// sorted top-6 insert (descending), static-indexed
__device__ __forceinline__ void ins6(float (&ts)[LTK], int (&ti)[LTK],
                                     float s, int idx)
{
  ts[LTK - 1] = s; ti[LTK - 1] = idx;
#pragma unroll
  for (int q = LTK - 1; q > 0; --q) {
    if (ts[q] > ts[q - 1]) {
      float a = ts[q]; ts[q] = ts[q - 1]; ts[q - 1] = a;
      int   b = ti[q]; ti[q] = ti[q - 1]; ti[q - 1] = b;
    }
  }
}

__device__ __forceinline__ float max16(const f32x16& v)
{
  float a = fmaxf(fmaxf(v[0], v[1]), fmaxf(v[2], v[3]));
  float b = fmaxf(fmaxf(v[4], v[5]), fmaxf(v[6], v[7]));
  float c = fmaxf(fmaxf(v[8], v[9]), fmaxf(v[10], v[11]));
  float d = fmaxf(fmaxf(v[12], v[13]), fmaxf(v[14], v[15]));
  return fmaxf(fmaxf(a, b), fmaxf(c, d));
}

__device__ __forceinline__ void gll16(const f16* src, f16* dst)
{
  __builtin_amdgcn_global_load_lds(
      (const __attribute__((address_space(1))) void*)(uintptr_t)src,
      (__attribute__((address_space(3))) void*)(uint32_t)(uintptr_t)dst,
      16, 0, 0);
}

// ---------------------------------------------------------------------------
// GEMM + fused per-lane top-k.  8 waves = 2 evid-waves x 4 batch-waves.
// Per block-iteration j: 256 evid rows x 256 batch cols, K=768.
// E staged in LDS (2 x 32 KB double buffer, global_load_lds, 4/wave/chunk);
// X (B-operand) loaded global->VGPR per chunk (L2-resident via XCD remap).
// Lockstep loop: vmcnt(0); barrier; [b-loads]; STAGE(kc+1); compute.
// b-loads are issued BEFORE the prefetch glls (vmcnt retires in order, so
// waiting on b must not imply waiting on the prefetch).
// ---------------------------------------------------------------------------
__global__ __launch_bounds__(512, 2) void gemm_topk(
    const f16* __restrict__ Ef, const f16* __restrict__ Xf,
    float* __restrict__ cs, int* __restrict__ ci)
{
  __shared__ f16 lds[2][16384];   // 2 x 32 KB, E frags only: frag = et*4+kk

  const int t    = threadIdx.x;
  const int lane = t & 63;
  const int w    = t >> 6;      // 0..7
  const int ew   = w >> 2;      // 0..1  evid-wave
  const int bw   = w & 3;       // 0..3  batch-wave

  // XCD-aware remap (id%8 = XCD): XCD x hosts bb in {8*(x>>2)..+7} (8 values
  // -> X working set 3 MB, L2-resident) and g in {4*(x&3)..+3} (4 values).
  const int id  = blockIdx.x;
  const int xcd = id & 7;
  const int q8  = id >> 3;                        // 0..31
  const int bb  = 8 * (xcd >> 2) + (q8 & 7);      // batch block 0..15
  const int g   = 4 * (xcd & 3) + (q8 >> 3);      // evidence group 0..15
  const int niter = 24 + (g < (NITER_TOT - 16 * 24) ? 1 : 0);

  // E staging: wave w stages e-tile et=w (4 KB = 4 glls per chunk)
  const uint32_t dbase = (uint32_t)(w * 4) * 512; // f16-element offset in buf

  // X source base for this wave's 2 batch-tiles
  const f16* xb0 = Xf + ((size_t)(bb * 8 + bw * 2 + 0) * KSTEPS) * 512 + lane * 8;
  const f16* xb1 = Xf + ((size_t)(bb * 8 + bw * 2 + 1) * KSTEPS) * 512 + lane * 8;

  float ts0[LTK], ts1[LTK]; int ti0[LTK], ti1[LTK];
#pragma unroll
  for (int q = 0; q < LTK; ++q) {
    ts0[q] = -INFINITY; ts1[q] = -INFINITY;
    ti0[q] = 0x7fffffff; ti1[q] = 0x7fffffff;
  }

  for (int j = 0; j < niter; ++j) {
    const int e32base = (g + NGRP * j) * 8;

    auto STAGE = [&](int kc, int bufi) {
      int et = e32base + w; if (et > E32N - 1) et = E32N - 1;
      const f16* s0 = Ef + ((size_t)et * KSTEPS + kc * 4) * 512 + lane * 8;
      f16* d0 = &lds[bufi][0] + dbase + lane * 8;
#pragma unroll
      for (int ff = 0; ff < 4; ++ff)
        gll16(s0 + ff * 512, d0 + ff * 512);
    };

    f32x16 acc0[4], acc1[4];
#pragma unroll
    for (int e = 0; e < 4; ++e) {
#pragma unroll
      for (int q = 0; q < 16; ++q) { acc0[e][q] = 0.f; acc1[e][q] = 0.f; }
    }

    STAGE(0, 0);
    for (int kc = 0; kc < KCN; ++kc) {
      asm volatile("s_waitcnt vmcnt(0)" ::: "memory"); // chunk-kc E landed
      __builtin_amdgcn_s_barrier();                    // all waves staged kc

      // b-frags for THIS chunk: issue before the prefetch glls (in-order
      // vmcnt retire: b-waits must not imply waiting on kc+1's staging).
      f16x8 b0[4], b1[4];
#pragma unroll
      for (int kk = 0; kk < 4; ++kk) {
        b0[kk] = *(const f16x8*)(xb0 + ((size_t)(kc * 4 + kk)) * 512);
        b1[kk] = *(const f16x8*)(xb1 + ((size_t)(kc * 4 + kk)) * 512);
      }
      asm volatile("" ::: "memory");   // pin b-loads before the glls below

      if (kc < KCN - 1) STAGE(kc + 1, (kc + 1) & 1);

      const f16* Lb = &lds[kc & 1][0];
#pragma unroll
      for (int kk = 0; kk < 4; ++kk) {
        f16x8 a[4];
#pragma unroll
        for (int e = 0; e < 4; ++e)
          a[e] = *(const f16x8*)(Lb + ((((ew * 4 + e) * 4 + kk)) << 9) + lane * 8);
#pragma unroll
        for (int e = 0; e < 4; ++e) {
          acc0[e] = __builtin_amdgcn_mfma_f32_32x32x16_f16(a[e], b0[kk], acc0[e], 0, 0, 0);
          acc1[e] = __builtin_amdgcn_mfma_f32_32x32x16_f16(a[e], b1[kk], acc1[e], 0, 0, 0);
        }
      }
    }

    // inserts, max-prefiltered per 16-value tile
    // C/D map: col=lane&31, row=(q&3)+8*(q>>2)+4*(lane>>5)
#pragma unroll
    for (int e = 0; e < 4; ++e) {
      const int ebase = e32base * 32 + (ew * 4 + e) * 32 + 4 * (lane >> 5);
      if (max16(acc0[e]) > ts0[LTK - 1]) {
#pragma unroll
        for (int q = 0; q < 16; ++q) {
          int eidx = ebase + (q & 3) + 8 * (q >> 2);
          float s = acc0[e][q];
          if (eidx < M_ROWS && s > ts0[LTK - 1]) ins6(ts0, ti0, s, eidx);
        }
      }
      if (max16(acc1[e]) > ts1[LTK - 1]) {
#pragma unroll
        for (int q = 0; q < 16; ++q) {
          int eidx = ebase + (q & 3) + 8 * (q >> 2);
          float s = acc1[e][q];
          if (eidx < M_ROWS && s > ts1[LTK - 1]) ins6(ts1, ti1, s, eidx);
        }
      }
    }
  }

  // ---- merge per batch-col: 4 lists (2 evid-waves x 2 lane-halves) -> top-12
  // LDS reuse: ds = 6144 floats at [0, 24 KB); di = 6144 ints at [32, 56) KB.
  // (Round-6 crash root-cause: di at +16 KB overlapped ds's 24 KB extent ->
  //  score floats corrupted indices -> final_merge read E at ~1e9*768 -> OOB.)
  __syncthreads();
  float* ds = (float*)&lds[0][0];
  int*   di = (int*)((char*)&lds[0][0] + 32 * 1024);
  {
    int half = lane >> 5, cl = lane & 31;
    int base0 = ((((ew * 2 + half) * 4 + bw) * 2 + 0) * 32 + cl) * LTK;
    int base1 = ((((ew * 2 + half) * 4 + bw) * 2 + 1) * 32 + cl) * LTK;
#pragma unroll
    for (int q = 0; q < LTK; ++q) {
      ds[base0 + q] = ts0[q]; di[base0 + q] = ti0[q];
      ds[base1 + q] = ts1[q]; di[base1 + q] = ti1[q];
    }
  }
  __syncthreads();
  if (t < 256) {
    int c = t; int bw2 = c >> 6, bt2 = (c >> 5) & 1, cl2 = c & 31;
    int hb[4];
#pragma unroll
    for (int u = 0; u < 4; ++u) {
      int ew2 = u >> 1, h2 = u & 1;
      hb[u] = ((((ew2 * 2 + h2) * 4 + bw2) * 2 + bt2) * 32 + cl2) * LTK;
    }
    const int row = bb * 256 + c;
    float* ocs = cs + ((size_t)row * NGRP + g) * CAND;
    int*   oci = ci + ((size_t)row * NGRP + g) * CAND;
    for (int o = 0; o < CAND; ++o) {
      float best = -INFINITY; int bidx = 0x7fffffff; int bu = 0, bq = 0;
#pragma unroll
      for (int u = 0; u < 4; ++u) {
        for (int q = 0; q < LTK; ++q) {
          float s = ds[hb[u] + q]; int id2 = di[hb[u] + q];
          if (s > best || (s == best && id2 < bidx)) { best = s; bidx = id2; bu = u; bq = q; }
        }
      }
      ds[hb[bu] + bq] = -INFINITY;
      ocs[o] = best; oci[o] = bidx;
    }
  }
}

// ---------------------------------------------------------------------------
// Final: per row merge 16*12=192 candidates -> approx top-16 -> fp64 rescore
// -> exact-ordered top-10 (absmax 0 in rounds 2-5).
// ---------------------------------------------------------------------------
__global__ __launch_bounds__(64) void final_merge(
    const float* __restrict__ x, const float* __restrict__ E,
    const float* __restrict__ cs, const int* __restrict__ ci,
    float* __restrict__ out)
{
  __shared__ float ls[192]; __shared__ int li[192];
  __shared__ int c16[16]; __shared__ double rs[16];
  const int row = blockIdx.x;
  const int lane = threadIdx.x;
  for (int q = lane; q < 192; q += 64) {
    ls[q] = cs[(size_t)row * 192 + q];
    li[q] = ci[(size_t)row * 192 + q];
  }
  __syncthreads();

  for (int o = 0; o < 16; ++o) {
    float bs = -INFINITY; int bi = 0x7fffffff; int bp = 0;
    for (int q = lane; q < 192; q += 64) {
      float s = ls[q];
      if (s > bs || (s == bs && li[q] < bi)) { bs = s; bi = li[q]; bp = q; }
    }
#pragma unroll
    for (int mk = 1; mk <= 32; mk <<= 1) {
      float qs = __shfl_xor(bs, mk, 64);
      int   qi = __shfl_xor(bi, mk, 64);
      int   qp = __shfl_xor(bp, mk, 64);
      if (qs > bs || (qs == bs && qi < bi)) { bs = qs; bi = qi; bp = qp; }
    }
    if (lane == 0) { c16[o] = bi; ls[bp] = -INFINITY; }
    __syncthreads();
  }

  {
    int cd = lane >> 2, p = lane & 3;
    int cid = c16[cd];
    if ((unsigned)cid >= M_ROWS) cid = 0;   // defensive: OOB -> wrong answer,
                                            // not a GPU memory fault
    const float* Er = E + (size_t)cid * D_DIM + p * 192;
    const float* Xr = x + (size_t)row * D_DIM + p * 192;
    double s = 0.0;
#pragma unroll 8
    for (int d = 0; d < 192; ++d) s += (double)Xr[d] * (double)Er[d];
    s += __shfl_xor(s, 1, 64);
    s += __shfl_xor(s, 2, 64);
    if (p == 0) rs[cd] = s;
  }
  __syncthreads();

  if (lane == 0) {
    for (int o = 0; o < K_TOP; ++o) {
      double bs = rs[0]; int bc = c16[0]; int b = 0;
      for (int q = 1; q < 16; ++q) {
        double v = rs[q]; int cq = c16[q];
        if (v > bs || (v == bs && cq < bc)) { bs = v; bc = cq; b = q; }
      }
      out[(size_t)row * K_TOP + o] = (float)bs;
      out[(size_t)B_ROWS * K_TOP + (size_t)row * K_TOP + o] = (float)bc;
      rs[b] = -1.0e300;
    }
  }
}

// ---------------------------------------------------------------------------
// Fallback (round-2 kernel) if ws_size is insufficient.
// ---------------------------------------------------------------------------
#define RB   16
#define GQ   64
#define MMF  4
#define NJ   391
#define NTF  1024
#define XPAD 772
#define DQ4  192

__global__ __launch_bounds__(NTF, 4) void retr_fused(
    const float* __restrict__ x, const float* __restrict__ E,
    float* __restrict__ out)
{
  __shared__ float smem[21248];
  const int t = threadIdx.x;
  const int r = t & 15;
  const int g = t >> 4;
  const int rb0 = blockIdx.x * RB;
  {
    const float4* xg = (const float4*)(x + (size_t)rb0 * D_DIM);
    for (int q = t; q < RB * DQ4; q += NTF) {
      int row = q / DQ4, c4 = q % DQ4;
      float4 v = xg[q];
      *(float4*)(smem + row * XPAD + c4 * 4) = v;
    }
  }
  __syncthreads();
  float ts[K_TOP]; int ti[K_TOP];
#pragma unroll
  for (int q = 0; q < K_TOP; ++q) { ts[q] = -INFINITY; ti[q] = 0x7fffffff; }
  const float4* xr4 = (const float4*)(smem + r * XPAD);
  for (int j = 0; j < NJ; ++j) {
    const int m0 = (g + (j << 6)) * MMF;
    const float4* ep[MMF];
#pragma unroll
    for (int mm = 0; mm < MMF; ++mm) {
      int ml = m0 + mm;
      int mc = (ml < M_ROWS) ? ml : (M_ROWS - 1);
      ep[mm] = (const float4*)(E + (size_t)mc * D_DIM);
    }
    float4 acc[MMF];
#pragma unroll
    for (int mm = 0; mm < MMF; ++mm) acc[mm] = make_float4(0.f, 0.f, 0.f, 0.f);
#pragma unroll 4
    for (int dq = 0; dq < DQ4; ++dq) {
      float4 xv = xr4[dq];
#pragma unroll
      for (int mm = 0; mm < MMF; ++mm) {
        float4 e = ep[mm][dq];
        acc[mm].x += e.x * xv.x; acc[mm].y += e.y * xv.y;
        acc[mm].z += e.z * xv.z; acc[mm].w += e.w * xv.w;
      }
    }
#pragma unroll
    for (int mm = 0; mm < MMF; ++mm) {
      int ml = m0 + mm;
      float s = (acc[mm].x + acc[mm].y) + (acc[mm].z + acc[mm].w);
      if (ml < M_ROWS && s > ts[K_TOP - 1]) {
        ts[K_TOP - 1] = s; ti[K_TOP - 1] = ml;
#pragma unroll
        for (int q = K_TOP - 1; q > 0; --q) {
          if (ts[q] > ts[q - 1]) {
            float tf = ts[q]; ts[q] = ts[q - 1]; ts[q - 1] = tf;
            int   tq = ti[q]; ti[q] = ti[q - 1]; ti[q - 1] = tq;
          }
        }
      }
    }
  }
  __syncthreads();
  float*  cs  = smem;
  int*    ci  = (int*)(smem + 10240);
  int*    cnd = (int*)(smem + 20480);
  double* rsd = (double*)(smem + 20736);
#pragma unroll
  for (int q = 0; q < K_TOP; ++q) {
    cs[(r * GQ + g) * K_TOP + q] = ts[q];
    ci[(r * GQ + g) * K_TOP + q] = ti[q];
  }
  __syncthreads();
  const int w = t >> 6;
  const int lane = t & 63;
  {
    float ms[K_TOP]; int mi[K_TOP];
#pragma unroll
    for (int q = 0; q < K_TOP; ++q) {
      ms[q] = cs[(w * GQ + lane) * K_TOP + q];
      mi[q] = ci[(w * GQ + lane) * K_TOP + q];
    }
    for (int o = 0; o < 16; ++o) {
      float hs = ms[0]; int hi = mi[0];
      float bs = hs;    int bi = hi;
#pragma unroll
      for (int mk = 1; mk <= 32; mk <<= 1) {
        float qs = __shfl_xor(bs, mk, 64);
        int   qi = __shfl_xor(bi, mk, 64);
        if (qs > bs || (qs == bs && qi < bi)) { bs = qs; bi = qi; }
      }
      bool win = (hs == bs) && (hi == bi);
      if (win) {
#pragma unroll
        for (int q = 0; q < K_TOP - 1; ++q) { ms[q] = ms[q + 1]; mi[q] = mi[q + 1]; }
        ms[K_TOP - 1] = -INFINITY; mi[K_TOP - 1] = 0x7fffffff;
      }
      if (lane == 0) cnd[w * 16 + o] = bi;
    }
  }
  __syncthreads();
  {
    int cand = lane >> 2, p = lane & 3;
    int cid = cnd[w * 16 + cand];
    const float* Er = E + (size_t)cid * D_DIM + p * 192;
    const float* Xr = x + (size_t)(rb0 + w) * D_DIM + p * 192;
    double s = 0.0;
#pragma unroll 8
    for (int d = 0; d < 192; ++d) s += (double)Xr[d] * (double)Er[d];
    s += __shfl_xor(s, 1, 64);
    s += __shfl_xor(s, 2, 64);
    if (p == 0) rsd[w * 16 + cand] = s;
  }
  __syncthreads();
  if (lane == 0) {
    const int row = rb0 + w;
    for (int o = 0; o < K_TOP; ++o) {
      double bsv = rsd[w * 16 + 0]; int bci = cnd[w * 16 + 0]; int b = 0;
      for (int q = 1; q < 16; ++q) {
        double v = rsd[w * 16 + q]; int c = cnd[w * 16 + q];
        if (v > bsv || (v == bsv && c < bci)) { bsv = v; bci = c; b = q; }
      }
      out[(size_t)row * K_TOP + o] = (float)bsv;
      out[(size_t)B_ROWS * K_TOP + (size_t)row * K_TOP + o] = (float)bci;
      rsd[w * 16 + b] = -1.0e300;
    }
  }
}

// ---------------------------------------------------------------------------
extern "C" void kernel_launch(void* const* d_in, const int* in_sizes, int n_in,
                              void* d_out, int out_size, void* d_ws, size_t ws_size,
                              hipStream_t stream) {
  const float* x = (const float*)d_in[0];
  const float* E = (const float*)d_in[1];
  float* out = (float*)d_out;

  if (ws_size < WS_NEED) {
    retr_fused<<<dim3(B_ROWS / RB), NTF, 0, stream>>>(x, E, out);
    return;
  }

  f16*   Xfp = (f16*)d_ws;
  f16*   Efp = (f16*)((char*)d_ws + EF_OFF);
  float* csp = (float*)((char*)d_ws + CS_OFF);
  int*   cip = (int*)((char*)d_ws + CI_OFF);

  convert_frag<<<dim3((B32N * KSTEPS * 64) / 256), 256, 0, stream>>>(x, Xfp, B32N);
  convert_frag<<<dim3((E32N * KSTEPS * 64) / 256), 256, 0, stream>>>(E, Efp, E32N);
  gemm_topk<<<dim3(NBB * NGRP), 512, 0, stream>>>(Efp, Xfp, csp, cip);
  final_merge<<<dim3(B_ROWS), 64, 0, stream>>>(x, E, csp, cip, out);
}

// Round 8
// 1187.154 us; speedup vs baseline: 1.3594x; 1.3594x over previous
//
#include <hip/hip_runtime.h>
#include <math.h>
#include <stdint.h>

#define B_ROWS 4096
#define D_DIM  768
#define M_ROWS 100000
#define K_TOP  10

// ---------------- MFMA-path constants ----------------
#define KSTEPS 48          // 768 / 16
#define E32N   3125        // evidence 32-row tiles
#define B32N   128         // batch 32-row tiles
#define NGRP   16          // evidence groups
#define NBB    16          // batch blocks (256 rows each)
#define NITER_TOT 391      // ceil(3125/8)
#define CAND   12          // candidates kept per (row, group)
#define KCN    12          // K-tiles of 64 per j
#define LTK    6           // per-lane top-k length

typedef _Float16 f16;
typedef _Float16 f16x8 __attribute__((ext_vector_type(8)));
typedef float   f32x16 __attribute__((ext_vector_type(16)));

// workspace layout (bytes)
#define XF_BYTES (128ull * 48 * 1024)
#define EF_OFF   XF_BYTES
#define EF_BYTES (3125ull * 48 * 1024)
#define CS_OFF   (EF_OFF + EF_BYTES)
#define CS_BYTES (4096ull * NGRP * CAND * 4)
#define CI_OFF   (CS_OFF + CS_BYTES)
#define CI_BYTES (4096ull * NGRP * CAND * 4)
#define WS_NEED  (CI_OFF + CI_BYTES)

// ---------------------------------------------------------------------------
// Convert fp32 [rows][768] -> f16 fragment-tiled [band32][ks48][lane64][j8].
// frag value (l,j) = src[band*32 + (l&31)][ks*16 + 8*(l>>5) + j]
// ---------------------------------------------------------------------------
__global__ __launch_bounds__(256) void convert_frag(
    const float* __restrict__ src, f16* __restrict__ dst, int nband)
{
  int tid  = blockIdx.x * 256 + threadIdx.x;
  int l    = tid & 63;
  int rest = tid >> 6;
  int ks   = rest % KSTEPS;
  int band = rest / KSTEPS;
  if (band >= nband) return;
  int row = band * 32 + (l & 31);
  int k0  = ks * 16 + 8 * (l >> 5);
  const float* s = src + (size_t)row * D_DIM + k0;
  float4 v0 = *(const float4*)s;
  float4 v1 = *(const float4*)(s + 4);
  f16x8 o;
  o[0] = (f16)v0.x; o[1] = (f16)v0.y; o[2] = (f16)v0.z; o[3] = (f16)v0.w;
  o[4] = (f16)v1.x; o[5] = (f16)v1.y; o[6] = (f16)v1.z; o[7] = (f16)v1.w;
  *(f16x8*)(dst + (((size_t)band * KSTEPS + ks) << 9) + l * 8) = o;
}

// sorted top-6 insert (descending), static-indexed
__device__ __forceinline__ void ins6(float (&ts)[LTK], int (&ti)[LTK],
                                     float s, int idx)
{
  ts[LTK - 1] = s; ti[LTK - 1] = idx;
#pragma unroll
  for (int q = LTK - 1; q > 0; --q) {
    if (ts[q] > ts[q - 1]) {
      float a = ts[q]; ts[q] = ts[q - 1]; ts[q - 1] = a;
      int   b = ti[q]; ti[q] = ti[q - 1]; ti[q - 1] = b;
    }
  }
}

__device__ __forceinline__ float max16(const f32x16& v)
{
  float a = fmaxf(fmaxf(v[0], v[1]), fmaxf(v[2], v[3]));
  float b = fmaxf(fmaxf(v[4], v[5]), fmaxf(v[6], v[7]));
  float c = fmaxf(fmaxf(v[8], v[9]), fmaxf(v[10], v[11]));
  float d = fmaxf(fmaxf(v[12], v[13]), fmaxf(v[14], v[15]));
  return fmaxf(fmaxf(a, b), fmaxf(c, d));
}

__device__ __forceinline__ void gll16(const f16* src, f16* dst)
{
  __builtin_amdgcn_global_load_lds(
      (const __attribute__((address_space(1))) void*)(uintptr_t)src,
      (__attribute__((address_space(3))) void*)(uint32_t)(uintptr_t)dst,
      16, 0, 0);
}

// ---------------------------------------------------------------------------
// GEMM + fused per-lane top-k.  8 waves = 2 evid-waves x 4 batch-waves.
// Per block-iteration j: 256 evid rows x 256 batch cols, K=768 (12 K-tiles
// of K=64). LDS 2 x 64 KB double buffer; per-buffer layout:
//   elem = half*16384 + (kk&1)*8192 + tidx*512 + lane*8
//   tidx 0..7 = E-tiles, 8..15 = X-tiles; half = kk>>1.
// 8-phase-style schedule (T3+T4+T5): per K-tile, 4 phases (one per kk):
//   P0: vmcnt(4); barrier; read kk0; MFMA(prio1)
//   P1: read kk1; ISSUE half0 of NEXT tile (4 glls/wave); barrier; MFMA
//   P2: vmcnt(4) [vmcnt(0) on final tile]; barrier; read kk2; MFMA
//   P3: read kk3; ISSUE half1 of NEXT tile; barrier; MFMA
// Counted vmcnt: the wait at P0/P2 leaves the most recent 4 loads (next
// half-tile) in flight; issue-to-use distance = 3 phases >= HBM latency.
// ---------------------------------------------------------------------------
__global__ __launch_bounds__(512, 2) void gemm_topk(
    const f16* __restrict__ Ef, const f16* __restrict__ Xf,
    float* __restrict__ cs, int* __restrict__ ci)
{
  __shared__ f16 lds[2][32768];   // 2 x 64 KB

  const int t    = threadIdx.x;
  const int lane = t & 63;
  const int w    = t >> 6;      // 0..7
  const int ew   = w >> 2;      // 0..1  evid-wave
  const int bw   = w & 3;       // 0..3  batch-wave

  // XCD-aware remap (round-4 proven): ids congruent mod 8 share an XCD.
  const int id = blockIdx.x;
  const int g  = (id & 7) + 8 * (id >> 7);        // evidence group 0..15
  const int bb = (id >> 3) & 15;                  // batch block 0..15
  const int niter = 24 + (g < (NITER_TOT - 16 * 24) ? 1 : 0);
  const int CTOT  = niter * KCN;                  // total K-tiles

  // staging roles: waves 0..3 stage E tiles et=2w,2w+1; waves 4..7 stage X
  // tiles bt=2(w-4),2(w-4)+1.  Per half-tile: 2 tiles x 2 kk = 4 glls/wave.
  auto STAGE_HALF = [&](int c2, int h) {
    const int j2   = c2 / KCN;
    const int kc2  = c2 % KCN;
    const int e32b = (g + NGRP * j2) * 8;
    const int bufi = c2 & 1;
    f16* dstb = &lds[bufi][h * 16384];
    if (w < 4) {
#pragma unroll
      for (int ti = 0; ti < 2; ++ti) {
        int et = 2 * w + ti;
        int e32 = e32b + et; if (e32 > E32N - 1) e32 = E32N - 1;
#pragma unroll
        for (int kh = 0; kh < 2; ++kh) {
          int kk = 2 * h + kh;
          const f16* s = Ef + ((size_t)e32 * KSTEPS + kc2 * 4 + kk) * 512 + lane * 8;
          gll16(s, dstb + kh * 8192 + et * 512 + lane * 8);
        }
      }
    } else {
#pragma unroll
      for (int ti = 0; ti < 2; ++ti) {
        int bt = 2 * (w - 4) + ti;
#pragma unroll
        for (int kh = 0; kh < 2; ++kh) {
          int kk = 2 * h + kh;
          const f16* s = Xf + ((size_t)(bb * 8 + bt) * KSTEPS + kc2 * 4 + kk) * 512 + lane * 8;
          gll16(s, dstb + kh * 8192 + (8 + bt) * 512 + lane * 8);
        }
      }
    }
  };

  float ts0[LTK], ts1[LTK]; int ti0[LTK], ti1[LTK];
#pragma unroll
  for (int q = 0; q < LTK; ++q) {
    ts0[q] = -INFINITY; ts1[q] = -INFINITY;
    ti0[q] = 0x7fffffff; ti1[q] = 0x7fffffff;
  }

  // prologue: both halves of tile 0
  STAGE_HALF(0, 0);
  STAGE_HALF(0, 1);

  int c = 0;
#pragma unroll 1
  for (int j = 0; j < niter; ++j) {
    const int e32base = (g + NGRP * j) * 8;

    f32x16 acc0[4], acc1[4];
#pragma unroll
    for (int e = 0; e < 4; ++e) {
#pragma unroll
      for (int q = 0; q < 16; ++q) { acc0[e][q] = 0.f; acc1[e][q] = 0.f; }
    }

#pragma unroll 1
    for (int kc = 0; kc < KCN; ++kc, ++c) {
      const f16* Lb = &lds[c & 1][0];
      const bool last = (c == CTOT - 1);

      // ---- P0: wait half0 (counted), sync, read kk0, MFMA ----
      asm volatile("s_waitcnt vmcnt(4)" ::: "memory");
      __builtin_amdgcn_s_barrier();
      __builtin_amdgcn_sched_barrier(0);
      f16x8 a0[4], b0[2];
      {
        const f16* Lp = Lb + lane * 8;                  // half 0, kk&1 = 0
#pragma unroll
        for (int e = 0; e < 4; ++e) a0[e] = *(const f16x8*)(Lp + (ew * 4 + e) * 512);
#pragma unroll
        for (int x2 = 0; x2 < 2; ++x2) b0[x2] = *(const f16x8*)(Lp + (8 + bw * 2 + x2) * 512);
      }
      __builtin_amdgcn_s_setprio(1);
#pragma unroll
      for (int e = 0; e < 4; ++e) {
        acc0[e] = __builtin_amdgcn_mfma_f32_32x32x16_f16(a0[e], b0[0], acc0[e], 0, 0, 0);
        acc1[e] = __builtin_amdgcn_mfma_f32_32x32x16_f16(a0[e], b0[1], acc1[e], 0, 0, 0);
      }
      __builtin_amdgcn_s_setprio(0);
      __builtin_amdgcn_sched_barrier(0);

      // ---- P1: read kk1, issue next-tile half0, sync, MFMA ----
      f16x8 a1[4], b1[2];
      {
        const f16* Lp = Lb + 8192 + lane * 8;           // half 0, kk&1 = 1
#pragma unroll
        for (int e = 0; e < 4; ++e) a1[e] = *(const f16x8*)(Lp + (ew * 4 + e) * 512);
#pragma unroll
        for (int x2 = 0; x2 < 2; ++x2) b1[x2] = *(const f16x8*)(Lp + (8 + bw * 2 + x2) * 512);
      }
      if (!last) STAGE_HALF(c + 1, 0);
      __builtin_amdgcn_s_barrier();
      __builtin_amdgcn_sched_barrier(0);
      __builtin_amdgcn_s_setprio(1);
#pragma unroll
      for (int e = 0; e < 4; ++e) {
        acc0[e] = __builtin_amdgcn_mfma_f32_32x32x16_f16(a1[e], b1[0], acc0[e], 0, 0, 0);
        acc1[e] = __builtin_amdgcn_mfma_f32_32x32x16_f16(a1[e], b1[1], acc1[e], 0, 0, 0);
      }
      __builtin_amdgcn_s_setprio(0);
      __builtin_amdgcn_sched_barrier(0);

      // ---- P2: wait half1 (counted; drain on final tile), sync, read kk2, MFMA
      if (last) { asm volatile("s_waitcnt vmcnt(0)" ::: "memory"); }
      else      { asm volatile("s_waitcnt vmcnt(4)" ::: "memory"); }
      __builtin_amdgcn_s_barrier();
      __builtin_amdgcn_sched_barrier(0);
      f16x8 a2[4], b2[2];
      {
        const f16* Lp = Lb + 16384 + lane * 8;          // half 1, kk&1 = 0
#pragma unroll
        for (int e = 0; e < 4; ++e) a2[e] = *(const f16x8*)(Lp + (ew * 4 + e) * 512);
#pragma unroll
        for (int x2 = 0; x2 < 2; ++x2) b2[x2] = *(const f16x8*)(Lp + (8 + bw * 2 + x2) * 512);
      }
      __builtin_amdgcn_s_setprio(1);
#pragma unroll
      for (int e = 0; e < 4; ++e) {
        acc0[e] = __builtin_amdgcn_mfma_f32_32x32x16_f16(a2[e], b2[0], acc0[e], 0, 0, 0);
        acc1[e] = __builtin_amdgcn_mfma_f32_32x32x16_f16(a2[e], b2[1], acc1[e], 0, 0, 0);
      }
      __builtin_amdgcn_s_setprio(0);
      __builtin_amdgcn_sched_barrier(0);

      // ---- P3: read kk3, issue next-tile half1, sync, MFMA ----
      f16x8 a3[4], b3[2];
      {
        const f16* Lp = Lb + 16384 + 8192 + lane * 8;   // half 1, kk&1 = 1
#pragma unroll
        for (int e = 0; e < 4; ++e) a3[e] = *(const f16x8*)(Lp + (ew * 4 + e) * 512);
#pragma unroll
        for (int x2 = 0; x2 < 2; ++x2) b3[x2] = *(const f16x8*)(Lp + (8 + bw * 2 + x2) * 512);
      }
      if (!last) STAGE_HALF(c + 1, 1);
      __builtin_amdgcn_s_barrier();
      __builtin_amdgcn_sched_barrier(0);
      __builtin_amdgcn_s_setprio(1);
#pragma unroll
      for (int e = 0; e < 4; ++e) {
        acc0[e] = __builtin_amdgcn_mfma_f32_32x32x16_f16(a3[e], b3[0], acc0[e], 0, 0, 0);
        acc1[e] = __builtin_amdgcn_mfma_f32_32x32x16_f16(a3[e], b3[1], acc1[e], 0, 0, 0);
      }
      __builtin_amdgcn_s_setprio(0);
      __builtin_amdgcn_sched_barrier(0);
    }

    // inserts, max-prefiltered per 16-value tile
    // C/D map: col=lane&31, row=(q&3)+8*(q>>2)+4*(lane>>5)
#pragma unroll
    for (int e = 0; e < 4; ++e) {
      const int ebase = e32base * 32 + (ew * 4 + e) * 32 + 4 * (lane >> 5);
      if (max16(acc0[e]) > ts0[LTK - 1]) {
#pragma unroll
        for (int q = 0; q < 16; ++q) {
          int eidx = ebase + (q & 3) + 8 * (q >> 2);
          float s = acc0[e][q];
          if (eidx < M_ROWS && s > ts0[LTK - 1]) ins6(ts0, ti0, s, eidx);
        }
      }
      if (max16(acc1[e]) > ts1[LTK - 1]) {
#pragma unroll
        for (int q = 0; q < 16; ++q) {
          int eidx = ebase + (q & 3) + 8 * (q >> 2);
          float s = acc1[e][q];
          if (eidx < M_ROWS && s > ts1[LTK - 1]) ins6(ts1, ti1, s, eidx);
        }
      }
    }
  }

  // ---- merge per batch-col: 4 lists (2 evid-waves x 2 lane-halves) -> top-12
  // LDS reuse: ds = 6144 floats at [0, 24 KB); di = 6144 ints at [32, 56) KB.
  __syncthreads();
  float* ds = (float*)&lds[0][0];
  int*   di = (int*)((char*)&lds[0][0] + 32 * 1024);
  {
    int half = lane >> 5, cl = lane & 31;
    int base0 = ((((ew * 2 + half) * 4 + bw) * 2 + 0) * 32 + cl) * LTK;
    int base1 = ((((ew * 2 + half) * 4 + bw) * 2 + 1) * 32 + cl) * LTK;
#pragma unroll
    for (int q = 0; q < LTK; ++q) {
      ds[base0 + q] = ts0[q]; di[base0 + q] = ti0[q];
      ds[base1 + q] = ts1[q]; di[base1 + q] = ti1[q];
    }
  }
  __syncthreads();
  if (t < 256) {
    int cth = t; int bw2 = cth >> 6, bt2 = (cth >> 5) & 1, cl2 = cth & 31;
    int hb[4];
#pragma unroll
    for (int u = 0; u < 4; ++u) {
      int ew2 = u >> 1, h2 = u & 1;
      hb[u] = ((((ew2 * 2 + h2) * 4 + bw2) * 2 + bt2) * 32 + cl2) * LTK;
    }
    const int row = bb * 256 + cth;
    float* ocs = cs + ((size_t)row * NGRP + g) * CAND;
    int*   oci = ci + ((size_t)row * NGRP + g) * CAND;
    for (int o = 0; o < CAND; ++o) {
      float best = -INFINITY; int bidx = 0x7fffffff; int bu = 0, bq = 0;
#pragma unroll
      for (int u = 0; u < 4; ++u) {
        for (int q = 0; q < LTK; ++q) {
          float s = ds[hb[u] + q]; int id2 = di[hb[u] + q];
          if (s > best || (s == best && id2 < bidx)) { best = s; bidx = id2; bu = u; bq = q; }
        }
      }
      ds[hb[bu] + bq] = -INFINITY;
      ocs[o] = best; oci[o] = bidx;
    }
  }
}

// ---------------------------------------------------------------------------
// Final: per row merge 16*12=192 candidates -> approx top-16 -> fp64 rescore
// -> exact-ordered top-10 (absmax 0 in rounds 2-5, 7).
// ---------------------------------------------------------------------------
__global__ __launch_bounds__(64) void final_merge(
    const float* __restrict__ x, const float* __restrict__ E,
    const float* __restrict__ cs, const int* __restrict__ ci,
    float* __restrict__ out)
{
  __shared__ float ls[192]; __shared__ int li[192];
  __shared__ int c16[16]; __shared__ double rs[16];
  const int row = blockIdx.x;
  const int lane = threadIdx.x;
  for (int q = lane; q < 192; q += 64) {
    ls[q] = cs[(size_t)row * 192 + q];
    li[q] = ci[(size_t)row * 192 + q];
  }
  __syncthreads();

  for (int o = 0; o < 16; ++o) {
    float bs = -INFINITY; int bi = 0x7fffffff; int bp = 0;
    for (int q = lane; q < 192; q += 64) {
      float s = ls[q];
      if (s > bs || (s == bs && li[q] < bi)) { bs = s; bi = li[q]; bp = q; }
    }
#pragma unroll
    for (int mk = 1; mk <= 32; mk <<= 1) {
      float qs = __shfl_xor(bs, mk, 64);
      int   qi = __shfl_xor(bi, mk, 64);
      int   qp = __shfl_xor(bp, mk, 64);
      if (qs > bs || (qs == bs && qi < bi)) { bs = qs; bi = qi; bp = qp; }
    }
    if (lane == 0) { c16[o] = bi; ls[bp] = -INFINITY; }
    __syncthreads();
  }

  {
    int cd = lane >> 2, p = lane & 3;
    int cid = c16[cd];
    if ((unsigned)cid >= M_ROWS) cid = 0;   // defensive: wrong answer, not fault
    const float* Er = E + (size_t)cid * D_DIM + p * 192;
    const float* Xr = x + (size_t)row * D_DIM + p * 192;
    double s = 0.0;
#pragma unroll 8
    for (int d = 0; d < 192; ++d) s += (double)Xr[d] * (double)Er[d];
    s += __shfl_xor(s, 1, 64);
    s += __shfl_xor(s, 2, 64);
    if (p == 0) rs[cd] = s;
  }
  __syncthreads();

  if (lane == 0) {
    for (int o = 0; o < K_TOP; ++o) {
      double bs = rs[0]; int bc = c16[0]; int b = 0;
      for (int q = 1; q < 16; ++q) {
        double v = rs[q]; int cq = c16[q];
        if (v > bs || (v == bs && cq < bc)) { bs = v; bc = cq; b = q; }
      }
      out[(size_t)row * K_TOP + o] = (float)bs;
      out[(size_t)B_ROWS * K_TOP + (size_t)row * K_TOP + o] = (float)bc;
      rs[b] = -1.0e300;
    }
  }
}

// ---------------------------------------------------------------------------
// Fallback (round-2 kernel) if ws_size is insufficient.
// ---------------------------------------------------------------------------
#define RB   16
#define GQ   64
#define MMF  4
#define NJ   391
#define NTF  1024
#define XPAD 772
#define DQ4  192

__global__ __launch_bounds__(NTF, 4) void retr_fused(
    const float* __restrict__ x, const float* __restrict__ E,
    float* __restrict__ out)
{
  __shared__ float smem[21248];
  const int t = threadIdx.x;
  const int r = t & 15;
  const int g = t >> 4;
  const int rb0 = blockIdx.x * RB;
  {
    const float4* xg = (const float4*)(x + (size_t)rb0 * D_DIM);
    for (int q = t; q < RB * DQ4; q += NTF) {
      int row = q / DQ4, c4 = q % DQ4;
      float4 v = xg[q];
      *(float4*)(smem + row * XPAD + c4 * 4) = v;
    }
  }
  __syncthreads();
  float ts[K_TOP]; int ti[K_TOP];
#pragma unroll
  for (int q = 0; q < K_TOP; ++q) { ts[q] = -INFINITY; ti[q] = 0x7fffffff; }
  const float4* xr4 = (const float4*)(smem + r * XPAD);
  for (int j = 0; j < NJ; ++j) {
    const int m0 = (g + (j << 6)) * MMF;
    const float4* ep[MMF];
#pragma unroll
    for (int mm = 0; mm < MMF; ++mm) {
      int ml = m0 + mm;
      int mc = (ml < M_ROWS) ? ml : (M_ROWS - 1);
      ep[mm] = (const float4*)(E + (size_t)mc * D_DIM);
    }
    float4 acc[MMF];
#pragma unroll
    for (int mm = 0; mm < MMF; ++mm) acc[mm] = make_float4(0.f, 0.f, 0.f, 0.f);
#pragma unroll 4
    for (int dq = 0; dq < DQ4; ++dq) {
      float4 xv = xr4[dq];
#pragma unroll
      for (int mm = 0; mm < MMF; ++mm) {
        float4 e = ep[mm][dq];
        acc[mm].x += e.x * xv.x; acc[mm].y += e.y * xv.y;
        acc[mm].z += e.z * xv.z; acc[mm].w += e.w * xv.w;
      }
    }
#pragma unroll
    for (int mm = 0; mm < MMF; ++mm) {
      int ml = m0 + mm;
      float s = (acc[mm].x + acc[mm].y) + (acc[mm].z + acc[mm].w);
      if (ml < M_ROWS && s > ts[K_TOP - 1]) {
        ts[K_TOP - 1] = s; ti[K_TOP - 1] = ml;
#pragma unroll
        for (int q = K_TOP - 1; q > 0; --q) {
          if (ts[q] > ts[q - 1]) {
            float tf = ts[q]; ts[q] = ts[q - 1]; ts[q - 1] = tf;
            int   tq = ti[q]; ti[q] = ti[q - 1]; ti[q - 1] = tq;
          }
        }
      }
    }
  }
  __syncthreads();
  float*  cs  = smem;
  int*    ci  = (int*)(smem + 10240);
  int*    cnd = (int*)(smem + 20480);
  double* rsd = (double*)(smem + 20736);
#pragma unroll
  for (int q = 0; q < K_TOP; ++q) {
    cs[(r * GQ + g) * K_TOP + q] = ts[q];
    ci[(r * GQ + g) * K_TOP + q] = ti[q];
  }
  __syncthreads();
  const int w = t >> 6;
  const int lane = t & 63;
  {
    float ms[K_TOP]; int mi[K_TOP];
#pragma unroll
    for (int q = 0; q < K_TOP; ++q) {
      ms[q] = cs[(w * GQ + lane) * K_TOP + q];
      mi[q] = ci[(w * GQ + lane) * K_TOP + q];
    }
    for (int o = 0; o < 16; ++o) {
      float hs = ms[0]; int hi = mi[0];
      float bs = hs;    int bi = hi;
#pragma unroll
      for (int mk = 1; mk <= 32; mk <<= 1) {
        float qs = __shfl_xor(bs, mk, 64);
        int   qi = __shfl_xor(bi, mk, 64);
        if (qs > bs || (qs == bs && qi < bi)) { bs = qs; bi = qi; }
      }
      bool win = (hs == bs) && (hi == bi);
      if (win) {
#pragma unroll
        for (int q = 0; q < K_TOP - 1; ++q) { ms[q] = ms[q + 1]; mi[q] = mi[q + 1]; }
        ms[K_TOP - 1] = -INFINITY; mi[K_TOP - 1] = 0x7fffffff;
      }
      if (lane == 0) cnd[w * 16 + o] = bi;
    }
  }
  __syncthreads();
  {
    int cand = lane >> 2, p = lane & 3;
    int cid = cnd[w * 16 + cand];
    const float* Er = E + (size_t)cid * D_DIM + p * 192;
    const float* Xr = x + (size_t)(rb0 + w) * D_DIM + p * 192;
    double s = 0.0;
#pragma unroll 8
    for (int d = 0; d < 192; ++d) s += (double)Xr[d] * (double)Er[d];
    s += __shfl_xor(s, 1, 64);
    s += __shfl_xor(s, 2, 64);
    if (p == 0) rsd[w * 16 + cand] = s;
  }
  __syncthreads();
  if (lane == 0) {
    const int row = rb0 + w;
    for (int o = 0; o < K_TOP; ++o) {
      double bsv = rsd[w * 16 + 0]; int bci = cnd[w * 16 + 0]; int b = 0;
      for (int q = 1; q < 16; ++q) {
        double v = rsd[w * 16 + q]; int c = cnd[w * 16 + q];
        if (v > bsv || (v == bsv && c < bci)) { bsv = v; bci = c; b = q; }
      }
      out[(size_t)row * K_TOP + o] = (float)bsv;
      out[(size_t)B_ROWS * K_TOP + (size_t)row * K_TOP + o] = (float)bci;
      rsd[w * 16 + b] = -1.0e300;
    }
  }
}

// ---------------------------------------------------------------------------
extern "C" void kernel_launch(void* const* d_in, const int* in_sizes, int n_in,
                              void* d_out, int out_size, void* d_ws, size_t ws_size,
                              hipStream_t stream) {
  const float* x = (const float*)d_in[0];
  const float* E = (const float*)d_in[1];
  float* out = (float*)d_out;

  if (ws_size < WS_NEED) {
    retr_fused<<<dim3(B_ROWS / RB), NTF, 0, stream>>>(x, E, out);
    return;
  }

  f16*   Xfp = (f16*)d_ws;
  f16*   Efp = (f16*)((char*)d_ws + EF_OFF);
  float* csp = (float*)((char*)d_ws + CS_OFF);
  int*   cip = (int*)((char*)d_ws + CI_OFF);

  convert_frag<<<dim3((B32N * KSTEPS * 64) / 256), 256, 0, stream>>>(x, Xfp, B32N);
  convert_frag<<<dim3((E32N * KSTEPS * 64) / 256), 256, 0, stream>>>(E, Efp, E32N);
  gemm_topk<<<dim3(NBB * NGRP), 512, 0, stream>>>(Efp, Xfp, csp, cip);
  final_merge<<<dim3(B_ROWS), 64, 0, stream>>>(x, E, csp, cip, out);
}

// Round 9
// 961.097 us; speedup vs baseline: 1.6791x; 1.2352x over previous
//
#include <hip/hip_runtime.h>
#include <math.h>
#include <stdint.h>

#define B_ROWS 4096
#define D_DIM  768
#define M_ROWS 100000
#define K_TOP  10

// ---------------- MFMA-path constants ----------------
#define KSTEPS 48          // 768 / 16
#define E32N   3125        // evidence 32-row tiles
#define B32N   128         // batch 32-row tiles
#define NGRP   16          // evidence groups
#define NBB    16          // batch blocks (256 rows each)
#define NITER_TOT 391      // ceil(3125/8)
#define CAND   12          // candidates kept per (row, group)
#define KCN    12          // k-chunks of 64
#define LTK    6           // per-lane top-k length

typedef _Float16 f16;
typedef _Float16 f16x8 __attribute__((ext_vector_type(8)));
typedef float   f32x16 __attribute__((ext_vector_type(16)));

// workspace layout (bytes)
#define XF_BYTES (128ull * 48 * 1024)
#define EF_OFF   XF_BYTES
#define EF_BYTES (3125ull * 48 * 1024)
#define CS_OFF   (EF_OFF + EF_BYTES)
#define CS_BYTES (4096ull * NGRP * CAND * 4)
#define CI_OFF   (CS_OFF + CS_BYTES)
#define CI_BYTES (4096ull * NGRP * CAND * 4)
#define WS_NEED  (CI_OFF + CI_BYTES)

// ---------------------------------------------------------------------------
// Convert fp32 [rows][768] -> f16 fragment-tiled [band32][ks48][lane64][j8].
// frag value (l,j) = src[band*32 + (l&31)][ks*16 + 8*(l>>5) + j]
// ---------------------------------------------------------------------------
__global__ __launch_bounds__(256) void convert_frag(
    const float* __restrict__ src, f16* __restrict__ dst, int nband)
{
  int tid  = blockIdx.x * 256 + threadIdx.x;
  int l    = tid & 63;
  int rest = tid >> 6;
  int ks   = rest % KSTEPS;
  int band = rest / KSTEPS;
  if (band >= nband) return;
  int row = band * 32 + (l & 31);
  int k0  = ks * 16 + 8 * (l >> 5);
  const float* s = src + (size_t)row * D_DIM + k0;
  float4 v0 = *(const float4*)s;
  float4 v1 = *(const float4*)(s + 4);
  f16x8 o;
  o[0] = (f16)v0.x; o[1] = (f16)v0.y; o[2] = (f16)v0.z; o[3] = (f16)v0.w;
  o[4] = (f16)v1.x; o[5] = (f16)v1.y; o[6] = (f16)v1.z; o[7] = (f16)v1.w;
  *(f16x8*)(dst + (((size_t)band * KSTEPS + ks) << 9) + l * 8) = o;
}

// sorted top-6 insert (descending), static-indexed
__device__ __forceinline__ void ins6(float (&ts)[LTK], int (&ti)[LTK],
                                     float s, int idx)
{
  ts[LTK - 1] = s; ti[LTK - 1] = idx;
#pragma unroll
  for (int q = LTK - 1; q > 0; --q) {
    if (ts[q] > ts[q - 1]) {
      float a = ts[q]; ts[q] = ts[q - 1]; ts[q - 1] = a;
      int   b = ti[q]; ti[q] = ti[q - 1]; ti[q - 1] = b;
    }
  }
}

__device__ __forceinline__ float max16(const f32x16& v)
{
  float a = fmaxf(fmaxf(v[0], v[1]), fmaxf(v[2], v[3]));
  float b = fmaxf(fmaxf(v[4], v[5]), fmaxf(v[6], v[7]));
  float c = fmaxf(fmaxf(v[8], v[9]), fmaxf(v[10], v[11]));
  float d = fmaxf(fmaxf(v[12], v[13]), fmaxf(v[14], v[15]));
  return fmaxf(fmaxf(a, b), fmaxf(c, d));
}

__device__ __forceinline__ void gll16(const f16* src, f16* dst)
{
  __builtin_amdgcn_global_load_lds(
      (const __attribute__((address_space(1))) void*)(uintptr_t)src,
      (__attribute__((address_space(3))) void*)(uint32_t)(uintptr_t)dst,
      16, 0, 0);
}

// ---------------------------------------------------------------------------
// GEMM + fused per-lane top-k.  Round-4 anchor schedule (812 us) with two
// wave-local optimizations (no sync-structure change):
//  (1) staging addresses hoisted to per-j base pointers + "+= 2048" per chunk
//      (kills the 64-bit mul chains that made VALUBusy 27%);
//  (2) fragment registers double-buffered (sets P/Q): kk+1's 6 ds_read_b128
//      issue before kk's 8 MFMAs, so LDS latency hides under the matrix pipe.
// 8 waves = 2 evid-waves x 4 batch-waves; per j: 256 evid x 256 batch, K=768.
// ---------------------------------------------------------------------------
__global__ __launch_bounds__(512, 2) void gemm_topk(
    const f16* __restrict__ Ef, const f16* __restrict__ Xf,
    float* __restrict__ cs, int* __restrict__ ci)
{
  __shared__ f16 lds[2][32768];   // 2 x 64KB; frags 0..31 = E, 32..63 = X

  const int t    = threadIdx.x;
  const int lane = t & 63;
  const int w    = t >> 6;      // 0..7
  const int ew   = w >> 2;      // 0..1  evid-wave
  const int bw   = w & 3;       // 0..3  batch-wave

  // XCD-aware remap (round-4 proven): ids congruent mod 8 share an XCD;
  // each XCD hosts all 16 batch-blocks of 2 evidence groups.
  const int id = blockIdx.x;
  const int g  = (id & 7) + 8 * (id >> 7);        // evidence group 0..15
  const int bb = (id >> 3) & 15;                  // batch block 0..15
  const int niter = 24 + (g < (NITER_TOT - 16 * 24) ? 1 : 0);

  // staging roles: waves 0..3 stage E tiles 2w,2w+1; waves 4..7 stage X.
  const bool isE = (w < 4);
  const uint32_t dbase = (isE ? (2 * w) * 2048 : 16384 + 2 * (w - 4) * 2048);
  f16* dst0 = &lds[0][0] + dbase + lane * 8;   // buf0 staging dst
  f16* dst1 = &lds[1][0] + dbase + lane * 8;   // buf1 staging dst

  // X sources are j-invariant (tiles contiguous: +KSTEPS*512 elems)
  const f16* xs0 = Xf + ((size_t)(bb * 8 + 2 * (w - 4)) * KSTEPS) * 512 + lane * 8;
  const f16* xs1 = xs0 + (size_t)KSTEPS * 512;

  // LDS read bases (offsets are compile-time immediates <= 64512 B)
  const f16* rb0p = &lds[0][0] + lane * 8;
  const f16* rb1p = &lds[1][0] + lane * 8;

  float ts0[LTK], ts1[LTK]; int ti0[LTK], ti1[LTK];
#pragma unroll
  for (int q = 0; q < LTK; ++q) {
    ts0[q] = -INFINITY; ts1[q] = -INFINITY;
    ti0[q] = 0x7fffffff; ti1[q] = 0x7fffffff;
  }

#define MFMA_ROW(A, B0, B1) \
  acc0[0] = __builtin_amdgcn_mfma_f32_32x32x16_f16(A##0, B0, acc0[0], 0, 0, 0); \
  acc1[0] = __builtin_amdgcn_mfma_f32_32x32x16_f16(A##0, B1, acc1[0], 0, 0, 0); \
  acc0[1] = __builtin_amdgcn_mfma_f32_32x32x16_f16(A##1, B0, acc0[1], 0, 0, 0); \
  acc1[1] = __builtin_amdgcn_mfma_f32_32x32x16_f16(A##1, B1, acc1[1], 0, 0, 0); \
  acc0[2] = __builtin_amdgcn_mfma_f32_32x32x16_f16(A##2, B0, acc0[2], 0, 0, 0); \
  acc1[2] = __builtin_amdgcn_mfma_f32_32x32x16_f16(A##2, B1, acc1[2], 0, 0, 0); \
  acc0[3] = __builtin_amdgcn_mfma_f32_32x32x16_f16(A##3, B0, acc0[3], 0, 0, 0); \
  acc1[3] = __builtin_amdgcn_mfma_f32_32x32x16_f16(A##3, B1, acc1[3], 0, 0, 0)

#define READ_SET(P, KK) \
  P##a0 = *(const f16x8*)(rp + ((ew * 4 + 0) * 4 + (KK)) * 512); \
  P##a1 = *(const f16x8*)(rp + ((ew * 4 + 1) * 4 + (KK)) * 512); \
  P##a2 = *(const f16x8*)(rp + ((ew * 4 + 2) * 4 + (KK)) * 512); \
  P##a3 = *(const f16x8*)(rp + ((ew * 4 + 3) * 4 + (KK)) * 512); \
  P##b0 = *(const f16x8*)(rp + (32 + (bw * 2 + 0) * 4 + (KK)) * 512); \
  P##b1 = *(const f16x8*)(rp + (32 + (bw * 2 + 1) * 4 + (KK)) * 512)

#pragma unroll 1
  for (int j = 0; j < niter; ++j) {
    const int e32base = (g + NGRP * j) * 8;

    // per-j staging source bases (one 64-bit mul per j, not per gll)
    const f16 *s0p, *s1p;
    if (isE) {
      int ea = e32base + 2 * w;     if (ea > E32N - 1) ea = E32N - 1;
      int eb = e32base + 2 * w + 1; if (eb > E32N - 1) eb = E32N - 1;
      s0p = Ef + (size_t)ea * (KSTEPS * 512) + lane * 8;
      s1p = Ef + (size_t)eb * (KSTEPS * 512) + lane * 8;
    } else { s0p = xs0; s1p = xs1; }

    f32x16 acc0[4], acc1[4];
#pragma unroll
    for (int e = 0; e < 4; ++e) {
#pragma unroll
      for (int q = 0; q < 16; ++q) { acc0[e][q] = 0.f; acc1[e][q] = 0.f; }
    }

    // stage chunk 0 into buf0 (safe: all waves passed last j's final barrier)
    {
#pragma unroll
      for (int ff = 0; ff < 4; ++ff) gll16(s0p + ff * 512, dst0 + ff * 512);
#pragma unroll
      for (int ff = 0; ff < 4; ++ff) gll16(s1p + ff * 512, dst0 + 2048 + ff * 512);
    }
    const f16* sc0 = s0p + 2048;   // chunk-1 source, advanced per chunk
    const f16* sc1 = s1p + 2048;

#pragma unroll 1
    for (int kc = 0; kc < KCN; ++kc) {
      asm volatile("s_waitcnt vmcnt(0)" ::: "memory"); // chunk-kc loads landed
      __builtin_amdgcn_s_barrier();                    // all waves staged kc

      const f16* rp = (kc & 1) ? rb1p : rb0p;          // read buffer
      f16* dp = (kc & 1) ? dst0 : dst1;                // next-chunk staging dst

      f16x8 pa0, pa1, pa2, pa3, pb0, pb1;              // set P (even kk)
      f16x8 qa0, qa1, qa2, qa3, qb0, qb1;              // set Q (odd kk)

      READ_SET(p, 0);                                  // P <- kk0
      if (kc < KCN - 1) {                              // stage chunk kc+1 early
#pragma unroll
        for (int ff = 0; ff < 4; ++ff) gll16(sc0 + ff * 512, dp + ff * 512);
#pragma unroll
        for (int ff = 0; ff < 4; ++ff) gll16(sc1 + ff * 512, dp + 2048 + ff * 512);
        sc0 += 2048; sc1 += 2048;
      }
      READ_SET(q, 1);                                  // Q <- kk1
      MFMA_ROW(pa, pb0, pb1);                          // MFMA kk0
      READ_SET(p, 2);                                  // P <- kk2
      MFMA_ROW(qa, qb0, qb1);                          // MFMA kk1
      READ_SET(q, 3);                                  // Q <- kk3
      MFMA_ROW(pa, pb0, pb1);                          // MFMA kk2
      MFMA_ROW(qa, qb0, qb1);                          // MFMA kk3
    }

    // inserts, max-prefiltered per 16-value tile
    // C/D map: col=lane&31, row=(q&3)+8*(q>>2)+4*(lane>>5)
#pragma unroll
    for (int e = 0; e < 4; ++e) {
      const int ebase = e32base * 32 + (ew * 4 + e) * 32 + 4 * (lane >> 5);
      if (max16(acc0[e]) > ts0[LTK - 1]) {
#pragma unroll
        for (int q = 0; q < 16; ++q) {
          int eidx = ebase + (q & 3) + 8 * (q >> 2);
          float s = acc0[e][q];
          if (eidx < M_ROWS && s > ts0[LTK - 1]) ins6(ts0, ti0, s, eidx);
        }
      }
      if (max16(acc1[e]) > ts1[LTK - 1]) {
#pragma unroll
        for (int q = 0; q < 16; ++q) {
          int eidx = ebase + (q & 3) + 8 * (q >> 2);
          float s = acc1[e][q];
          if (eidx < M_ROWS && s > ts1[LTK - 1]) ins6(ts1, ti1, s, eidx);
        }
      }
    }
  }
#undef MFMA_ROW
#undef READ_SET

  // ---- merge per batch-col: 4 lists (2 evid-waves x 2 lane-halves) -> top-12
  // LDS reuse: ds = 6144 floats at [0, 24 KB); di = 6144 ints at [32, 56) KB.
  __syncthreads();
  float* ds = (float*)&lds[0][0];
  int*   di = (int*)((char*)&lds[0][0] + 32 * 1024);
  {
    int half = lane >> 5, cl = lane & 31;
    int base0 = ((((ew * 2 + half) * 4 + bw) * 2 + 0) * 32 + cl) * LTK;
    int base1 = ((((ew * 2 + half) * 4 + bw) * 2 + 1) * 32 + cl) * LTK;
#pragma unroll
    for (int q = 0; q < LTK; ++q) {
      ds[base0 + q] = ts0[q]; di[base0 + q] = ti0[q];
      ds[base1 + q] = ts1[q]; di[base1 + q] = ti1[q];
    }
  }
  __syncthreads();
  if (t < 256) {
    int c = t; int bw2 = c >> 6, bt2 = (c >> 5) & 1, cl2 = c & 31;
    int hb[4];
#pragma unroll
    for (int u = 0; u < 4; ++u) {
      int ew2 = u >> 1, h2 = u & 1;
      hb[u] = ((((ew2 * 2 + h2) * 4 + bw2) * 2 + bt2) * 32 + cl2) * LTK;
    }
    const int row = bb * 256 + c;
    float* ocs = cs + ((size_t)row * NGRP + g) * CAND;
    int*   oci = ci + ((size_t)row * NGRP + g) * CAND;
    for (int o = 0; o < CAND; ++o) {
      float best = -INFINITY; int bidx = 0x7fffffff; int bu = 0, bq = 0;
#pragma unroll
      for (int u = 0; u < 4; ++u) {
        for (int q = 0; q < LTK; ++q) {
          float s = ds[hb[u] + q]; int id2 = di[hb[u] + q];
          if (s > best || (s == best && id2 < bidx)) { best = s; bidx = id2; bu = u; bq = q; }
        }
      }
      ds[hb[bu] + bq] = -INFINITY;
      ocs[o] = best; oci[o] = bidx;
    }
  }
}

// ---------------------------------------------------------------------------
// Final: per row merge 16*12=192 candidates -> approx top-16 -> fp64 rescore
// -> exact-ordered top-10 (absmax 0 in rounds 2-5, 7, 8).
// ---------------------------------------------------------------------------
__global__ __launch_bounds__(64) void final_merge(
    const float* __restrict__ x, const float* __restrict__ E,
    const float* __restrict__ cs, const int* __restrict__ ci,
    float* __restrict__ out)
{
  __shared__ float ls[192]; __shared__ int li[192];
  __shared__ int c16[16]; __shared__ double rs[16];
  const int row = blockIdx.x;
  const int lane = threadIdx.x;
  for (int q = lane; q < 192; q += 64) {
    ls[q] = cs[(size_t)row * 192 + q];
    li[q] = ci[(size_t)row * 192 + q];
  }
  __syncthreads();

  for (int o = 0; o < 16; ++o) {
    float bs = -INFINITY; int bi = 0x7fffffff; int bp = 0;
    for (int q = lane; q < 192; q += 64) {
      float s = ls[q];
      if (s > bs || (s == bs && li[q] < bi)) { bs = s; bi = li[q]; bp = q; }
    }
#pragma unroll
    for (int mk = 1; mk <= 32; mk <<= 1) {
      float qs = __shfl_xor(bs, mk, 64);
      int   qi = __shfl_xor(bi, mk, 64);
      int   qp = __shfl_xor(bp, mk, 64);
      if (qs > bs || (qs == bs && qi < bi)) { bs = qs; bi = qi; bp = qp; }
    }
    if (lane == 0) { c16[o] = bi; ls[bp] = -INFINITY; }
    __syncthreads();
  }

  {
    int cd = lane >> 2, p = lane & 3;
    int cid = c16[cd];
    if ((unsigned)cid >= M_ROWS) cid = 0;   // defensive: wrong answer, not fault
    const float* Er = E + (size_t)cid * D_DIM + p * 192;
    const float* Xr = x + (size_t)row * D_DIM + p * 192;
    double s = 0.0;
#pragma unroll 8
    for (int d = 0; d < 192; ++d) s += (double)Xr[d] * (double)Er[d];
    s += __shfl_xor(s, 1, 64);
    s += __shfl_xor(s, 2, 64);
    if (p == 0) rs[cd] = s;
  }
  __syncthreads();

  if (lane == 0) {
    for (int o = 0; o < K_TOP; ++o) {
      double bs = rs[0]; int bc = c16[0]; int b = 0;
      for (int q = 1; q < 16; ++q) {
        double v = rs[q]; int cq = c16[q];
        if (v > bs || (v == bs && cq < bc)) { bs = v; bc = cq; b = q; }
      }
      out[(size_t)row * K_TOP + o] = (float)bs;
      out[(size_t)B_ROWS * K_TOP + (size_t)row * K_TOP + o] = (float)bc;
      rs[b] = -1.0e300;
    }
  }
}

// ---------------------------------------------------------------------------
// Fallback (round-2 kernel) if ws_size is insufficient.
// ---------------------------------------------------------------------------
#define RB   16
#define GQ   64
#define MMF  4
#define NJ   391
#define NTF  1024
#define XPAD 772
#define DQ4  192

__global__ __launch_bounds__(NTF, 4) void retr_fused(
    const float* __restrict__ x, const float* __restrict__ E,
    float* __restrict__ out)
{
  __shared__ float smem[21248];
  const int t = threadIdx.x;
  const int r = t & 15;
  const int g = t >> 4;
  const int rb0 = blockIdx.x * RB;
  {
    const float4* xg = (const float4*)(x + (size_t)rb0 * D_DIM);
    for (int q = t; q < RB * DQ4; q += NTF) {
      int row = q / DQ4, c4 = q % DQ4;
      float4 v = xg[q];
      *(float4*)(smem + row * XPAD + c4 * 4) = v;
    }
  }
  __syncthreads();
  float ts[K_TOP]; int ti[K_TOP];
#pragma unroll
  for (int q = 0; q < K_TOP; ++q) { ts[q] = -INFINITY; ti[q] = 0x7fffffff; }
  const float4* xr4 = (const float4*)(smem + r * XPAD);
  for (int j = 0; j < NJ; ++j) {
    const int m0 = (g + (j << 6)) * MMF;
    const float4* ep[MMF];
#pragma unroll
    for (int mm = 0; mm < MMF; ++mm) {
      int ml = m0 + mm;
      int mc = (ml < M_ROWS) ? ml : (M_ROWS - 1);
      ep[mm] = (const float4*)(E + (size_t)mc * D_DIM);
    }
    float4 acc[MMF];
#pragma unroll
    for (int mm = 0; mm < MMF; ++mm) acc[mm] = make_float4(0.f, 0.f, 0.f, 0.f);
#pragma unroll 4
    for (int dq = 0; dq < DQ4; ++dq) {
      float4 xv = xr4[dq];
#pragma unroll
      for (int mm = 0; mm < MMF; ++mm) {
        float4 e = ep[mm][dq];
        acc[mm].x += e.x * xv.x; acc[mm].y += e.y * xv.y;
        acc[mm].z += e.z * xv.z; acc[mm].w += e.w * xv.w;
      }
    }
#pragma unroll
    for (int mm = 0; mm < MMF; ++mm) {
      int ml = m0 + mm;
      float s = (acc[mm].x + acc[mm].y) + (acc[mm].z + acc[mm].w);
      if (ml < M_ROWS && s > ts[K_TOP - 1]) {
        ts[K_TOP - 1] = s; ti[K_TOP - 1] = ml;
#pragma unroll
        for (int q = K_TOP - 1; q > 0; --q) {
          if (ts[q] > ts[q - 1]) {
            float tf = ts[q]; ts[q] = ts[q - 1]; ts[q - 1] = tf;
            int   tq = ti[q]; ti[q] = ti[q - 1]; ti[q - 1] = tq;
          }
        }
      }
    }
  }
  __syncthreads();
  float*  cs  = smem;
  int*    ci  = (int*)(smem + 10240);
  int*    cnd = (int*)(smem + 20480);
  double* rsd = (double*)(smem + 20736);
#pragma unroll
  for (int q = 0; q < K_TOP; ++q) {
    cs[(r * GQ + g) * K_TOP + q] = ts[q];
    ci[(r * GQ + g) * K_TOP + q] = ti[q];
  }
  __syncthreads();
  const int w = t >> 6;
  const int lane = t & 63;
  {
    float ms[K_TOP]; int mi[K_TOP];
#pragma unroll
    for (int q = 0; q < K_TOP; ++q) {
      ms[q] = cs[(w * GQ + lane) * K_TOP + q];
      mi[q] = ci[(w * GQ + lane) * K_TOP + q];
    }
    for (int o = 0; o < 16; ++o) {
      float hs = ms[0]; int hi = mi[0];
      float bs = hs;    int bi = hi;
#pragma unroll
      for (int mk = 1; mk <= 32; mk <<= 1) {
        float qs = __shfl_xor(bs, mk, 64);
        int   qi = __shfl_xor(bi, mk, 64);
        if (qs > bs || (qs == bs && qi < bi)) { bs = qs; bi = qi; }
      }
      bool win = (hs == bs) && (hi == bi);
      if (win) {
#pragma unroll
        for (int q = 0; q < K_TOP - 1; ++q) { ms[q] = ms[q + 1]; mi[q] = mi[q + 1]; }
        ms[K_TOP - 1] = -INFINITY; mi[K_TOP - 1] = 0x7fffffff;
      }
      if (lane == 0) cnd[w * 16 + o] = bi;
    }
  }
  __syncthreads();
  {
    int cand = lane >> 2, p = lane & 3;
    int cid = cnd[w * 16 + cand];
    const float* Er = E + (size_t)cid * D_DIM + p * 192;
    const float* Xr = x + (size_t)(rb0 + w) * D_DIM + p * 192;
    double s = 0.0;
#pragma unroll 8
    for (int d = 0; d < 192; ++d) s += (double)Xr[d] * (double)Er[d];
    s += __shfl_xor(s, 1, 64);
    s += __shfl_xor(s, 2, 64);
    if (p == 0) rsd[w * 16 + cand] = s;
  }
  __syncthreads();
  if (lane == 0) {
    const int row = rb0 + w;
    for (int o = 0; o < K_TOP; ++o) {
      double bsv = rsd[w * 16 + 0]; int bci = cnd[w * 16 + 0]; int b = 0;
      for (int q = 1; q < 16; ++q) {
        double v = rsd[w * 16 + q]; int c = cnd[w * 16 + q];
        if (v > bsv || (v == bsv && c < bci)) { bsv = v; bci = c; b = q; }
      }
      out[(size_t)row * K_TOP + o] = (float)bsv;
      out[(size_t)B_ROWS * K_TOP + (size_t)row * K_TOP + o] = (float)bci;
      rsd[w * 16 + b] = -1.0e300;
    }
  }
}

// ---------------------------------------------------------------------------
extern "C" void kernel_launch(void* const* d_in, const int* in_sizes, int n_in,
                              void* d_out, int out_size, void* d_ws, size_t ws_size,
                              hipStream_t stream) {
  const float* x = (const float*)d_in[0];
  const float* E = (const float*)d_in[1];
  float* out = (float*)d_out;

  if (ws_size < WS_NEED) {
    retr_fused<<<dim3(B_ROWS / RB), NTF, 0, stream>>>(x, E, out);
    return;
  }

  f16*   Xfp = (f16*)d_ws;
  f16*   Efp = (f16*)((char*)d_ws + EF_OFF);
  float* csp = (float*)((char*)d_ws + CS_OFF);
  int*   cip = (int*)((char*)d_ws + CI_OFF);

  convert_frag<<<dim3((B32N * KSTEPS * 64) / 256), 256, 0, stream>>>(x, Xfp, B32N);
  convert_frag<<<dim3((E32N * KSTEPS * 64) / 256), 256, 0, stream>>>(E, Efp, E32N);
  gemm_topk<<<dim3(NBB * NGRP), 512, 0, stream>>>(Efp, Xfp, csp, cip);
  final_merge<<<dim3(B_ROWS), 64, 0, stream>>>(x, E, csp, cip, out);
}